// Round 9
// baseline (1974.600 us; speedup 1.0000x reference)
//
#include <hip/hip_runtime.h>
#include <math.h>

#define NDIM 64
typedef float f32x2 __attribute__((ext_vector_type(2)));

#define MEMFENCE() asm volatile("" ::: "memory")

// Broadcast lane `lane`'s value to all lanes (uniform / SGPR).
__device__ __forceinline__ float rl(float v, int lane) {
    return __uint_as_float((unsigned)__builtin_amdgcn_readlane(__float_as_uint(v), lane));
}

// DPP add step with compile-time control/row mask.
template<int CTRL, int ROW_MASK>
__device__ __forceinline__ float dpp_add(float x) {
    int m = __builtin_amdgcn_update_dpp(0, __float_as_int(x), CTRL, ROW_MASK, 0xf, true);
    return x + __int_as_float(m);
}
// Full-wave64 sum via DPP; total lands in lane 63, broadcast via readlane.
__device__ __forceinline__ float wave_sum(float x) {
    x = dpp_add<0x111, 0xf>(x);   // row_shr:1
    x = dpp_add<0x112, 0xf>(x);   // row_shr:2
    x = dpp_add<0x114, 0xf>(x);   // row_shr:4
    x = dpp_add<0x118, 0xf>(x);   // row_shr:8
    x = dpp_add<0x142, 0xa>(x);   // row_bcast:15 -> rows 1,3
    x = dpp_add<0x143, 0xc>(x);   // row_bcast:31 -> row 3
    return rl(x, 63);
}
__device__ __forceinline__ float wave_min(float v) {
    #pragma unroll
    for (int off = 1; off < 64; off <<= 1) v = fminf(v, __shfl_xor(v, off, 64));
    return v;
}
__device__ __forceinline__ float wave_max(float v) {
    #pragma unroll
    for (int off = 1; off < 64; off <<= 1) v = fmaxf(v, __shfl_xor(v, off, 64));
    return v;
}

// Dual-matrix Householder chunk: iterations k in [K0, K1) on matrices A and B
// interleaved for ILP (two independent dependency chains per wave). Columns
// <= K0 inert. v/w broadcast via per-wave-per-matrix LDS float4 buffers.
template<int K0, int K1>
__device__ __forceinline__ void tri_chunk2(f32x2 (&rA)[32], f32x2 (&rB)[32],
                                           float& colA, float& colB,
                                           float& dA, float& dB,
                                           float& e2A, float& e2B, const int t,
                                           float4* vbA, float4* wbA,
                                           float4* vbB, float4* wbB) {
    float* vpA = (float*)vbA; float* wpA = (float*)wbA;
    float* vpB = (float*)vbB; float* wpB = (float*)wbB;
    constexpr int Q0 = K0 / 4;
    #pragma unroll 1
    for (int k = K0; k < K1; ++k) {
        float aktA = (t > k) ? colA : 0.0f;
        float aktB = (t > k) ? colB : 0.0f;
        float s2A = wave_sum(aktA * aktA);
        float s2B = wave_sum(aktB * aktB);
        float a1A = rl(aktA, k + 1);
        float a1B = rl(aktB, k + 1);
        float sgA = sqrtf(s2A), sgB = sqrtf(s2B);
        float alA = (a1A >= 0.0f) ? -sgA : sgA;
        float alB = (a1B >= 0.0f) ? -sgB : sgB;
        e2A = (t == k) ? s2A : e2A;
        e2B = (t == k) ? s2B : e2B;
        float vA = aktA - ((t == k + 1) ? alA : 0.0f);
        float vB = aktB - ((t == k + 1) ? alB : 0.0f);
        float vtvA = 2.0f * (s2A - alA * a1A);
        float vtvB = 2.0f * (s2B - alB * a1B);
        float beA = (vtvA > 1e-30f) ? 2.0f * __builtin_amdgcn_rcpf(vtvA) : 0.0f;
        float beB = (vtvB > 1e-30f) ? 2.0f * __builtin_amdgcn_rcpf(vtvB) : 0.0f;
        vpA[t] = vA;
        vpB[t] = vB;
        MEMFENCE();

        // u = A*v for both matrices, streaming v quads from LDS
        f32x2 accA = {0.0f, 0.0f};
        f32x2 accB = {0.0f, 0.0f};
        #pragma unroll
        for (int q = Q0; q < 16; ++q) {
            float4 va = vbA[q];
            float4 vb = vbB[q];
            f32x2 va01; va01.x = va.x; va01.y = va.y;
            f32x2 va23; va23.x = va.z; va23.y = va.w;
            f32x2 vb01; vb01.x = vb.x; vb01.y = vb.y;
            f32x2 vb23; vb23.x = vb.z; vb23.y = vb.w;
            accA = __builtin_elementwise_fma(rA[2 * q],     va01, accA);
            accB = __builtin_elementwise_fma(rB[2 * q],     vb01, accB);
            accA = __builtin_elementwise_fma(rA[2 * q + 1], va23, accA);
            accB = __builtin_elementwise_fma(rB[2 * q + 1], vb23, accB);
        }
        float uA = accA.x + accA.y;
        float uB = accB.x + accB.y;
        float vtuA = wave_sum(vA * uA);
        float vtuB = wave_sum(vB * uB);
        float wA = (t > k) ? fmaf(-0.5f * beA * beA * vtuA, vA, beA * uA) : 0.0f;
        float wB = (t > k) ? fmaf(-0.5f * beB * beB * vtuB, vB, beB * uB) : 0.0f;
        wpA[t] = wA;
        wpB[t] = wB;
        MEMFENCE();
        f32x2 nvA; nvA.x = -vA; nvA.y = -vA;
        f32x2 nwA; nwA.x = -wA; nwA.y = -wA;
        f32x2 nvB; nvB.x = -vB; nvB.y = -vB;
        f32x2 nwB; nwB.x = -wB; nwB.y = -wB;

        // rank-2 update both matrices
        #pragma unroll
        for (int q = Q0; q < 16; ++q) {
            float4 va = vbA[q];
            float4 wa = wbA[q];
            float4 vb = vbB[q];
            float4 wb = wbB[q];
            f32x2 va01; va01.x = va.x; va01.y = va.y;
            f32x2 va23; va23.x = va.z; va23.y = va.w;
            f32x2 wa01; wa01.x = wa.x; wa01.y = wa.y;
            f32x2 wa23; wa23.x = wa.z; wa23.y = wa.w;
            f32x2 vb01; vb01.x = vb.x; vb01.y = vb.y;
            f32x2 vb23; vb23.x = vb.z; vb23.y = vb.w;
            f32x2 wb01; wb01.x = wb.x; wb01.y = wb.y;
            f32x2 wb23; wb23.x = wb.z; wb23.y = wb.w;
            rA[2 * q]     = __builtin_elementwise_fma(nvA, wa01,
                            __builtin_elementwise_fma(nwA, va01, rA[2 * q]));
            rB[2 * q]     = __builtin_elementwise_fma(nvB, wb01,
                            __builtin_elementwise_fma(nwB, vb01, rB[2 * q]));
            rA[2 * q + 1] = __builtin_elementwise_fma(nvA, wa23,
                            __builtin_elementwise_fma(nwA, va23, rA[2 * q + 1]));
            rB[2 * q + 1] = __builtin_elementwise_fma(nvB, wb23,
                            __builtin_elementwise_fma(nwB, vb23, rB[2 * q + 1]));
        }

        // next column values (static selects within the chunk window)
        float ncA = colA, ncB = colB;
        #pragma unroll
        for (int j = K0 + 1; j <= K1; ++j) {
            if (j == k + 1) {
                ncA = (j & 1) ? rA[j >> 1].y : rA[j >> 1].x;
                ncB = (j & 1) ? rB[j >> 1].y : rB[j >> 1].x;
            }
        }
        colA = ncA; colB = ncB;
        dA = (t == k + 1) ? ncA : dA;
        dB = (t == k + 1) ? ncB : dB;
    }
}

// One-time prep: Sa = 0.5(A+A^T), Bh = 0.5B, Bt = 0.5B^T, Ch = 0.5C, Ct = 0.5C^T.
__global__ __launch_bounds__(64)
void prep_kernel(const float* __restrict__ A, const float* __restrict__ B,
                 const float* __restrict__ C, float* __restrict__ ws) {
    const int t = threadIdx.x;
    float* Sa = ws;
    float* Bh = ws + 4096;
    float* Bt = ws + 8192;
    float* Ch = ws + 12288;
    float* Ct = ws + 16384;
    for (int j = 0; j < NDIM; ++j) {
        Sa[t * NDIM + j] = 0.5f * (A[t * NDIM + j] + A[j * NDIM + t]);
        Bh[t * NDIM + j] = 0.5f * B[t * NDIM + j];
        Bt[t * NDIM + j] = 0.5f * B[j * NDIM + t];
        Ch[t * NDIM + j] = 0.5f * C[t * NDIM + j];
        Ct[t * NDIM + j] = 0.5f * C[j * NDIM + t];
    }
}

// 256 threads = 4 waves; each wave processes TWO matrices (interleaved chains).
// Per-wave private LDS slices; no barriers.
__global__ __launch_bounds__(256, 2)
void bispec_eig_kernel(const float* __restrict__ x, const float* __restrict__ y,
                       const float* __restrict__ ws, const int* __restrict__ idxp,
                       float* __restrict__ out, int batch) {
    const int t = threadIdx.x & 63;
    const int wv = threadIdx.x >> 6;
    const int bA = blockIdx.x * 8 + wv * 2;
    const int bB = bA + 1;
    if (bA >= batch) return;

    __shared__ float4 vb4s[4][2][16];
    __shared__ float4 wb4s[4][2][16];
    __shared__ float2 des[4][2][64];
    float4* vbA = vb4s[wv][0];
    float4* wbA = wb4s[wv][0];
    float4* vbB = vb4s[wv][1];
    float4* wbB = wb4s[wv][1];
    float2* depA = des[wv][0];
    float2* depB = des[wv][1];

    const bool hasB = (bB < batch);
    const float xiA = x[bA * NDIM + t];
    const float yiA = y[bA * NDIM + t];
    const float xiB = hasB ? x[bB * NDIM + t] : 0.0f;
    const float yiB = hasB ? y[bB * NDIM + t] : 0.0f;
    ((float*)vbA)[t] = xiA;
    ((float*)wbA)[t] = yiA;
    ((float*)vbB)[t] = xiB;
    ((float*)wbB)[t] = yiB;
    MEMFENCE();

    const float4* Sa4 = (const float4*)(ws + t * NDIM);
    const float4* Bh4 = (const float4*)(ws + 4096 + t * NDIM);
    const float4* Bt4 = (const float4*)(ws + 8192 + t * NDIM);
    const float4* Ch4 = (const float4*)(ws + 12288 + t * NDIM);
    const float4* Ct4 = (const float4*)(ws + 16384 + t * NDIM);

    // r_sym[t][j] = Sa + Bh*x[j] + Bt*x[t] + Ch*y[j] + Ct*y[t]; ws loaded once
    // per wave, used for both matrices.
    f32x2 rA[32], rB[32];
    #pragma unroll
    for (int q = 0; q < 16; ++q) {
        float4 sa = Sa4[q], bh = Bh4[q], bt = Bt4[q], ch = Ch4[q], ct = Ct4[q];
        float4 xqA = vbA[q], yqA = wbA[q];
        float4 xqB = vbB[q], yqB = wbB[q];
        float a0 = fmaf(bh.x, xqA.x, fmaf(bt.x, xiA, fmaf(ch.x, yqA.x, fmaf(ct.x, yiA, sa.x))));
        float a1 = fmaf(bh.y, xqA.y, fmaf(bt.y, xiA, fmaf(ch.y, yqA.y, fmaf(ct.y, yiA, sa.y))));
        float a2 = fmaf(bh.z, xqA.z, fmaf(bt.z, xiA, fmaf(ch.z, yqA.z, fmaf(ct.z, yiA, sa.z))));
        float a3 = fmaf(bh.w, xqA.w, fmaf(bt.w, xiA, fmaf(ch.w, yqA.w, fmaf(ct.w, yiA, sa.w))));
        float b0 = fmaf(bh.x, xqB.x, fmaf(bt.x, xiB, fmaf(ch.x, yqB.x, fmaf(ct.x, yiB, sa.x))));
        float b1 = fmaf(bh.y, xqB.y, fmaf(bt.y, xiB, fmaf(ch.y, yqB.y, fmaf(ct.y, yiB, sa.y))));
        float b2 = fmaf(bh.z, xqB.z, fmaf(bt.z, xiB, fmaf(ch.z, yqB.z, fmaf(ct.z, yiB, sa.z))));
        float b3 = fmaf(bh.w, xqB.w, fmaf(bt.w, xiB, fmaf(ch.w, yqB.w, fmaf(ct.w, yiB, sa.w))));
        rA[2 * q].x = a0;     rA[2 * q].y = a1;
        rA[2 * q + 1].x = a2; rA[2 * q + 1].y = a3;
        rB[2 * q].x = b0;     rB[2 * q].y = b1;
        rB[2 * q + 1].x = b2; rB[2 * q + 1].y = b3;
    }

    // ---- Dual Householder tridiagonalization ----
    float colA = rA[0].x, colB = rB[0].x;
    float dA = (t == 0) ? rA[0].x : 0.0f;
    float dB = (t == 0) ? rB[0].x : 0.0f;
    float e2A = 0.0f, e2B = 0.0f;
    tri_chunk2< 0,  8>(rA, rB, colA, colB, dA, dB, e2A, e2B, t, vbA, wbA, vbB, wbB);
    tri_chunk2< 8, 16>(rA, rB, colA, colB, dA, dB, e2A, e2B, t, vbA, wbA, vbB, wbB);
    tri_chunk2<16, 24>(rA, rB, colA, colB, dA, dB, e2A, e2B, t, vbA, wbA, vbB, wbB);
    tri_chunk2<24, 32>(rA, rB, colA, colB, dA, dB, e2A, e2B, t, vbA, wbA, vbB, wbB);
    tri_chunk2<32, 40>(rA, rB, colA, colB, dA, dB, e2A, e2B, t, vbA, wbA, vbB, wbB);
    tri_chunk2<40, 48>(rA, rB, colA, colB, dA, dB, e2A, e2B, t, vbA, wbA, vbB, wbB);
    tri_chunk2<48, 56>(rA, rB, colA, colB, dA, dB, e2A, e2B, t, vbA, wbA, vbB, wbB);
    tri_chunk2<56, 62>(rA, rB, colA, colB, dA, dB, e2A, e2B, t, vbA, wbA, vbB, wbB);

    // Trailing 2x2: e[62] = lane63's colreg; d[63] = r[63].
    float e62A = rl(colA, 63);
    float e62B = rl(colB, 63);
    e2A = (t == 62) ? e62A * e62A : e2A;
    e2B = (t == 62) ? e62B * e62B : e2B;
    dA = (t == 63) ? rA[31].y : dA;
    dB = (t == 63) ? rB[31].y : dB;

    // Stash (d_t, e^2_{t-1}) pairs for the Sturm phase.
    float epA = __shfl_up(e2A, 1, 64);
    float epB = __shfl_up(e2B, 1, 64);
    epA = (t == 0) ? 0.0f : epA;
    epB = (t == 0) ? 0.0f : epB;
    float2 pA; pA.x = dA; pA.y = epA;
    float2 pB; pB.x = dB; pB.y = epB;
    depA[t] = pA;
    depB[t] = pB;
    MEMFENCE();

    // Gershgorin bounds
    float eaA = sqrtf(e2A), eaB = sqrtf(e2B);
    float evA = __shfl_up(eaA, 1, 64);
    float evB = __shfl_up(eaB, 1, 64);
    evA = (t == 0) ? 0.0f : evA;
    evB = (t == 0) ? 0.0f : evB;
    float loA = wave_min(dA - (eaA + evA));
    float hiA = wave_max(dA + (eaA + evA));
    float loB = wave_min(dB - (eaB + evB));
    float hiB = wave_max(dB + (eaB + evB));
    float padA = 1e-3f + 1e-5f * fmaxf(fabsf(loA), fabsf(hiA));
    float padB = 1e-3f + 1e-5f * fmaxf(fabsf(loB), fabsf(hiB));
    loA -= padA; hiA += padA;
    loB -= padB; hiB += padB;

    int idx = idxp[0];
    idx = idx < 0 ? 0 : (idx > NDIM - 1 ? NDIM - 1 : idx);

    // Dual 64-way multisection on the Sturm sequences (3 iters)
    #pragma unroll 1
    for (int it = 0; it < 3; ++it) {
        float wdA = (hiA - loA) * (1.0f / 65.0f);
        float wdB = (hiB - loB) * (1.0f / 65.0f);
        float sA = loA + wdA * (float)(t + 1);
        float sB = loB + wdB * (float)(t + 1);
        float2 q0A = depA[0];
        float2 q0B = depB[0];
        float qA = q0A.x - sA;
        float qB = q0B.x - sB;
        qA = (fabsf(qA) < 1e-12f) ? -1e-12f : qA;
        qB = (fabsf(qB) < 1e-12f) ? -1e-12f : qB;
        int cntA = (qA < 0.0f) ? 1 : 0;
        int cntB = (qB < 0.0f) ? 1 : 0;
        #pragma unroll
        for (int i = 1; i < NDIM; ++i) {
            float2 piA = depA[i];
            float2 piB = depB[i];
            qA = piA.x - sA - piA.y * __builtin_amdgcn_rcpf(qA);
            qB = piB.x - sB - piB.y * __builtin_amdgcn_rcpf(qB);
            qA = (fabsf(qA) < 1e-12f) ? -1e-12f : qA;
            qB = (fabsf(qB) < 1e-12f) ? -1e-12f : qB;
            cntA += (qA < 0.0f) ? 1 : 0;
            cntB += (qB < 0.0f) ? 1 : 0;
        }
        unsigned long long mA = __ballot(cntA <= idx);
        unsigned long long mB = __ballot(cntB <= idx);
        int pa = (int)__popcll(mA);
        int pb = (int)__popcll(mB);
        float nloA = loA + wdA * (float)pa;
        float nhiA = loA + wdA * (float)(pa + 1);
        float nloB = loB + wdB * (float)pb;
        float nhiB = loB + wdB * (float)(pb + 1);
        loA = nloA;
        hiA = (pa >= 64) ? hiA : nhiA;
        loB = nloB;
        hiB = (pb >= 64) ? hiB : nhiB;
    }

    if (t == 0) {
        out[bA] = 0.5f * (loA + hiA);
        if (hasB) out[bB] = 0.5f * (loB + hiB);
    }
}

extern "C" void kernel_launch(void* const* d_in, const int* in_sizes, int n_in,
                              void* d_out, int out_size, void* d_ws, size_t ws_size,
                              hipStream_t stream) {
    const float* x = (const float*)d_in[0];
    const float* y = (const float*)d_in[1];
    const float* A = (const float*)d_in[2];
    const float* B = (const float*)d_in[3];
    const float* C = (const float*)d_in[4];
    const int* idxp = (const int*)d_in[5];
    float* out = (float*)d_out;
    float* ws = (float*)d_ws;
    int batch = in_sizes[0] / NDIM;

    hipLaunchKernelGGL(prep_kernel, dim3(1), dim3(64), 0, stream, A, B, C, ws);
    hipLaunchKernelGGL(bispec_eig_kernel, dim3((batch + 7) / 8), dim3(256), 0, stream,
                       x, y, ws, idxp, out, batch);
}

// Round 10
// 846.027 us; speedup vs baseline: 2.3340x; 2.3340x over previous
//
#include <hip/hip_runtime.h>
#include <math.h>

#define NDIM 64
typedef float f32x2 __attribute__((ext_vector_type(2)));

#define MEMFENCE() asm volatile("" ::: "memory")

// Broadcast lane `lane`'s value to all lanes (uniform / SGPR).
__device__ __forceinline__ float rl(float v, int lane) {
    return __uint_as_float((unsigned)__builtin_amdgcn_readlane(__float_as_uint(v), lane));
}

// DPP add step with compile-time control/row mask.
template<int CTRL, int ROW_MASK>
__device__ __forceinline__ float dpp_add(float x) {
    int m = __builtin_amdgcn_update_dpp(0, __float_as_int(x), CTRL, ROW_MASK, 0xf, true);
    return x + __int_as_float(m);
}
// Full-wave64 sum via DPP; total lands in lane 63, broadcast via readlane.
__device__ __forceinline__ float wave_sum(float x) {
    x = dpp_add<0x111, 0xf>(x);   // row_shr:1
    x = dpp_add<0x112, 0xf>(x);   // row_shr:2
    x = dpp_add<0x114, 0xf>(x);   // row_shr:4
    x = dpp_add<0x118, 0xf>(x);   // row_shr:8
    x = dpp_add<0x142, 0xa>(x);   // row_bcast:15 -> rows 1,3
    x = dpp_add<0x143, 0xc>(x);   // row_bcast:31 -> row 3
    return rl(x, 63);
}
__device__ __forceinline__ float wave_min(float v) {
    #pragma unroll
    for (int off = 1; off < 64; off <<= 1) v = fminf(v, __shfl_xor(v, off, 64));
    return v;
}
__device__ __forceinline__ float wave_max(float v) {
    #pragma unroll
    for (int off = 1; off < 64; off <<= 1) v = fmaxf(v, __shfl_xor(v, off, 64));
    return v;
}

// Householder iterations k in [K0, K1); K0 multiple of 8. Latency-hiding
// restructure: the column akt is published to LDS at the END of the previous
// iteration (gap to its read = wave_sum+alpha chain); the w broadcast is
// eliminated algebraically: v_t*w[j] + w_t*v[j] = p1*u[j] + p2*a[j] plus a
// closed-form scalar fix at j==k+1. u's write->read gap is covered by the
// vtu wave_sum. Single-wave DS ordering (in-order DS pipe), no barriers.
template<int K0, int K1>
__device__ __forceinline__ void tri_chunk(f32x2 (&r2)[32], float& colreg,
                                          float& dval, float& e2val, const int t,
                                          float4* ab4, float4* ub4) {
    float* abp = (float*)ab4;
    float* ubp = (float*)ub4;
    constexpr int Q0 = K0 / 4;
    #pragma unroll 1
    for (int k = K0; k < K1; ++k) {
        float akt = (t > k) ? colreg : 0.0f;      // local copy (LDS already has it)
        float s2 = wave_sum(akt * akt);
        float a1 = rl(akt, k + 1);
        float sigma = sqrtf(s2);
        float alpha = (a1 >= 0.0f) ? -sigma : sigma;  // e[k]=alpha, e[k]^2=s2
        e2val = (t == k) ? s2 : e2val;
        float vt = akt - ((t == k + 1) ? alpha : 0.0f);
        float vtv = 2.0f * (s2 - alpha * a1);
        float beta = (vtv > 1e-30f) ? 2.0f * __builtin_amdgcn_rcpf(vtv) : 0.0f;

        // pre-update r_t[k+1] (static window select)
        float pre_col = colreg;
        #pragma unroll
        for (int j = K0 + 1; j <= K1; ++j)
            if (j == k + 1) pre_col = (j & 1) ? r2[j >> 1].y : r2[j >> 1].x;

        // u_t = sum_j a[j]*r_t[j] - alpha*r_t[k+1]   (a[] streamed from LDS)
        f32x2 acc = {0.0f, 0.0f};
        #pragma unroll
        for (int q = Q0; q < 16; ++q) {
            float4 aq = ab4[q];
            f32x2 a01; a01.x = aq.x; a01.y = aq.y;
            f32x2 a23; a23.x = aq.z; a23.y = aq.w;
            acc = __builtin_elementwise_fma(r2[2 * q],     a01, acc);
            acc = __builtin_elementwise_fma(r2[2 * q + 1], a23, acc);
        }
        float ut = (acc.x + acc.y) - alpha * pre_col;
        float vtu = wave_sum(vt * ut);            // vt==0 for t<=k masks inactive rows
        float u_store = (t > k) ? ut : 0.0f;
        ubp[t] = u_store;
        MEMFENCE();
        float c  = 0.5f * beta * beta * vtu;
        float wt = (t > k) ? (beta * ut - c * vt) : 0.0f;
        float p1 = vt * beta;
        float p2 = wt - c * vt;
        float uk1 = rl(u_store, k + 1);
        float ncol = pre_col - p1 * uk1 - p2 * a1 + alpha * p2;  // r_t[k+1] post-update

        f32x2 np1; np1.x = -p1; np1.y = -p1;
        f32x2 np2; np2.x = -p2; np2.y = -p2;
        // rank-2 update: r[j] -= p1*u[j] + p2*a[j]  (u read gap covered above)
        #pragma unroll
        for (int q = Q0; q < 16; ++q) {
            float4 uq = ub4[q];
            float4 aq = ab4[q];
            f32x2 u01; u01.x = uq.x; u01.y = uq.y;
            f32x2 u23; u23.x = uq.z; u23.y = uq.w;
            f32x2 a01; a01.x = aq.x; a01.y = aq.y;
            f32x2 a23; a23.x = aq.z; a23.y = aq.w;
            r2[2 * q]     = __builtin_elementwise_fma(np1, u01,
                            __builtin_elementwise_fma(np2, a01, r2[2 * q]));
            r2[2 * q + 1] = __builtin_elementwise_fma(np1, u23,
                            __builtin_elementwise_fma(np2, a23, r2[2 * q + 1]));
        }
        // exact element k+1 (delta term) via the closed form
        #pragma unroll
        for (int j = K0 + 1; j <= K1; ++j) {
            if (j == k + 1) {
                if (j & 1) r2[j >> 1].y = ncol; else r2[j >> 1].x = ncol;
            }
        }
        colreg = ncol;
        dval = (t == k + 1) ? ncol : dval;        // d[k+1] final after iter k
        // publish next column early; consumed only after next wave_sum+alpha
        abp[t] = (t > k + 1) ? ncol : 0.0f;
        MEMFENCE();
    }
}

// One-time prep: Sa = 0.5(A+A^T), Bh = 0.5B, Bt = 0.5B^T, Ch = 0.5C, Ct = 0.5C^T.
__global__ __launch_bounds__(64)
void prep_kernel(const float* __restrict__ A, const float* __restrict__ B,
                 const float* __restrict__ C, float* __restrict__ ws) {
    const int t = threadIdx.x;
    float* Sa = ws;
    float* Bh = ws + 4096;
    float* Bt = ws + 8192;
    float* Ch = ws + 12288;
    float* Ct = ws + 16384;
    for (int j = 0; j < NDIM; ++j) {
        Sa[t * NDIM + j] = 0.5f * (A[t * NDIM + j] + A[j * NDIM + t]);
        Bh[t * NDIM + j] = 0.5f * B[t * NDIM + j];
        Bt[t * NDIM + j] = 0.5f * B[j * NDIM + t];
        Ch[t * NDIM + j] = 0.5f * C[t * NDIM + j];
        Ct[t * NDIM + j] = 0.5f * C[j * NDIM + t];
    }
}

// 256 threads = 4 independent waves = 4 matrices per block. Per-wave private
// LDS slices; no barriers.
__global__ __launch_bounds__(256, 2)
void bispec_eig_kernel(const float* __restrict__ x, const float* __restrict__ y,
                       const float* __restrict__ ws, const int* __restrict__ idxp,
                       float* __restrict__ out, int batch) {
    const int t = threadIdx.x & 63;
    const int wv = threadIdx.x >> 6;
    const int b = blockIdx.x * 4 + wv;
    if (b >= batch) return;

    __shared__ float4 ab4s[4][16];
    __shared__ float4 ub4s[4][16];
    __shared__ float2 des[4][64];
    float4* ab4 = ab4s[wv];
    float4* ub4 = ub4s[wv];
    float2* dep = des[wv];

    const float xi = x[b * NDIM + t];
    const float yi = y[b * NDIM + t];
    ((float*)ab4)[t] = xi;            // x broadcast (buffer reused for akt later)
    ((float*)ub4)[t] = yi;            // y broadcast (buffer reused for u later)
    MEMFENCE();

    const float4* Sa4 = (const float4*)(ws + t * NDIM);
    const float4* Bh4 = (const float4*)(ws + 4096 + t * NDIM);
    const float4* Bt4 = (const float4*)(ws + 8192 + t * NDIM);
    const float4* Ch4 = (const float4*)(ws + 12288 + t * NDIM);
    const float4* Ct4 = (const float4*)(ws + 16384 + t * NDIM);

    // r_sym[t][j] = Sa + Bh*x[j] + Bt*x[t] + Ch*y[j] + Ct*y[t]
    f32x2 r2[32];
    #pragma unroll
    for (int q = 0; q < 16; ++q) {
        float4 sa = Sa4[q], bh = Bh4[q], bt = Bt4[q], ch = Ch4[q], ct = Ct4[q];
        float4 xq = ab4[q], yq = ub4[q];
        float e0 = fmaf(bh.x, xq.x, fmaf(bt.x, xi, fmaf(ch.x, yq.x, fmaf(ct.x, yi, sa.x))));
        float e1 = fmaf(bh.y, xq.y, fmaf(bt.y, xi, fmaf(ch.y, yq.y, fmaf(ct.y, yi, sa.y))));
        float e2 = fmaf(bh.z, xq.z, fmaf(bt.z, xi, fmaf(ch.z, yq.z, fmaf(ct.z, yi, sa.z))));
        float e3 = fmaf(bh.w, xq.w, fmaf(bt.w, xi, fmaf(ch.w, yq.w, fmaf(ct.w, yi, sa.w))));
        r2[2 * q].x = e0;     r2[2 * q].y = e1;
        r2[2 * q + 1].x = e2; r2[2 * q + 1].y = e3;
    }

    // ---- Householder tridiagonalization ----
    float colreg = r2[0].x;
    float dval = (t == 0) ? r2[0].x : 0.0f;
    float e2val = 0.0f;
    // publish akt for k=0
    ((float*)ab4)[t] = (t > 0) ? colreg : 0.0f;
    MEMFENCE();
    tri_chunk< 0,  8>(r2, colreg, dval, e2val, t, ab4, ub4);
    tri_chunk< 8, 16>(r2, colreg, dval, e2val, t, ab4, ub4);
    tri_chunk<16, 24>(r2, colreg, dval, e2val, t, ab4, ub4);
    tri_chunk<24, 32>(r2, colreg, dval, e2val, t, ab4, ub4);
    tri_chunk<32, 40>(r2, colreg, dval, e2val, t, ab4, ub4);
    tri_chunk<40, 48>(r2, colreg, dval, e2val, t, ab4, ub4);
    tri_chunk<48, 56>(r2, colreg, dval, e2val, t, ab4, ub4);
    tri_chunk<56, 62>(r2, colreg, dval, e2val, t, ab4, ub4);

    // Trailing 2x2: e[62] = lane63's colreg; d[63] = r[63].
    float e62 = rl(colreg, 63);
    e2val = (t == 62) ? e62 * e62 : e2val;
    dval = (t == 63) ? r2[31].y : dval;

    // Stash (d_t, e^2_{t-1}) pairs for the Sturm phase.
    float e2prev = __shfl_up(e2val, 1, 64);
    e2prev = (t == 0) ? 0.0f : e2prev;
    float2 dp; dp.x = dval; dp.y = e2prev;
    dep[t] = dp;
    MEMFENCE();

    // Gershgorin bounds
    float eabs = sqrtf(e2val);
    float eprev = __shfl_up(eabs, 1, 64);
    eprev = (t == 0) ? 0.0f : eprev;
    float rad = eabs + eprev;
    float lo = wave_min(dval - rad);
    float hi = wave_max(dval + rad);
    float pad = 1e-3f + 1e-5f * fmaxf(fabsf(lo), fabsf(hi));
    lo -= pad;
    hi += pad;

    int idx = idxp[0];
    idx = idx < 0 ? 0 : (idx > NDIM - 1 ? NDIM - 1 : idx);

    // 64-way multisection on the Sturm sequence (3 iters)
    #pragma unroll 1
    for (int it = 0; it < 3; ++it) {
        float wdt = (hi - lo) * (1.0f / 65.0f);
        float s = lo + wdt * (float)(t + 1);
        float2 p0 = dep[0];
        float q = p0.x - s;
        q = (fabsf(q) < 1e-12f) ? -1e-12f : q;
        int cnt = (q < 0.0f) ? 1 : 0;
        #pragma unroll
        for (int i = 1; i < NDIM; ++i) {
            float2 pi = dep[i];
            q = pi.x - s - pi.y * __builtin_amdgcn_rcpf(q);
            q = (fabsf(q) < 1e-12f) ? -1e-12f : q;
            cnt += (q < 0.0f) ? 1 : 0;
        }
        unsigned long long m = __ballot(cnt <= idx);
        int p = (int)__popcll(m);
        float nlo = lo + wdt * (float)p;
        float nhi = lo + wdt * (float)(p + 1);
        lo = nlo;
        hi = (p >= 64) ? hi : nhi;
    }

    if (t == 0) out[b] = 0.5f * (lo + hi);
}

extern "C" void kernel_launch(void* const* d_in, const int* in_sizes, int n_in,
                              void* d_out, int out_size, void* d_ws, size_t ws_size,
                              hipStream_t stream) {
    const float* x = (const float*)d_in[0];
    const float* y = (const float*)d_in[1];
    const float* A = (const float*)d_in[2];
    const float* B = (const float*)d_in[3];
    const float* C = (const float*)d_in[4];
    const int* idxp = (const int*)d_in[5];
    float* out = (float*)d_out;
    float* ws = (float*)d_ws;
    int batch = in_sizes[0] / NDIM;

    hipLaunchKernelGGL(prep_kernel, dim3(1), dim3(64), 0, stream, A, B, C, ws);
    hipLaunchKernelGGL(bispec_eig_kernel, dim3((batch + 3) / 4), dim3(256), 0, stream,
                       x, y, ws, idxp, out, batch);
}